// Round 1
// baseline (2232.876 us; speedup 1.0000x reference)
//
#include <hip/hip_runtime.h>

typedef unsigned short u16;
typedef unsigned int u32;
typedef short bf16x8 __attribute__((ext_vector_type(8)));
typedef float f32x4 __attribute__((ext_vector_type(4)));
typedef u16 u16x4 __attribute__((ext_vector_type(4)));

typedef u32 __attribute__((address_space(1))) gl_u32;
typedef u32 __attribute__((address_space(3))) lds_u32;

#define INV_TAU 1.6666666666666667f

__device__ __forceinline__ u16 f2b(float f) {
    u32 u = __builtin_bit_cast(u32, f);
    u += 0x7fffu + ((u >> 16) & 1u);
    return (u16)(u >> 16);
}
__device__ __forceinline__ float b2f(u16 h) {
    u32 u = ((u32)h) << 16;
    return __builtin_bit_cast(float, u);
}
__device__ __forceinline__ float sigm(float x) { return 1.0f / (1.0f + __expf(-x)); }

// ---------------------------------------------------------------------------
// Generic C = A @ W^T (+bias) GEMM, bf16 inputs, fp32 accumulate.
// A: (M,K) row-major bf16 bits, lda elems. W: (N,K) row-major bf16 bits, ldw.
// 128x128 tile, BK=32, 4 waves (2x2), each wave 4x4 frags of 16x16x32 MFMA.
// mode 0: write Cb bf16 (ldcb). mode 1: write Cf fp32 (ldc). mode 2: RVQ
//   epilogue (N must be 128): step += e; if(upd_cum) cum += e, decCum=bf16(cum).
// ---------------------------------------------------------------------------
__global__ __launch_bounds__(256, 2) void gemm_bt(
    const u16* __restrict__ A, int lda,
    const u16* __restrict__ W, int ldw,
    const float* __restrict__ bias,
    float* __restrict__ Cf, int ldc,
    u16* __restrict__ Cb, int ldcb,
    int Ksz, int mode,
    float* __restrict__ stepP, float* __restrict__ cumP, u16* __restrict__ decCum,
    int step_init, int upd_cum)
{
    __shared__ __align__(16) u16 As[128 * 32];
    __shared__ __align__(16) u16 Ws[128 * 32];
    const int tid = threadIdx.x;
    const int wv = tid >> 6;
    const int l = tid & 63;
    const int wr = wv >> 1, wc = wv & 1;
    const int tm = blockIdx.y << 7, tn = blockIdx.x << 7;
    const int srow = l >> 2;            // staging row within 16-row wave chunk
    const int scol = (l & 3) << 3;      // staging col (elems)
    const int frow = l & 15;
    const int kq = (l >> 4) << 3;

    f32x4 acc[4][4] = {};

    for (int k0 = 0; k0 < Ksz; k0 += 32) {
#pragma unroll
        for (int r = 0; r < 2; ++r) {
            const int row = (r << 6) + (wv << 4) + srow;
            const u16* ga = A + (size_t)(tm + row) * lda + (k0 + scol);
            const u16* gw = W + (size_t)(tn + row) * ldw + (k0 + scol);
            u16* la = As + (r << 11) + (wv << 9);   // wave-uniform LDS base
            u16* lw = Ws + (r << 11) + (wv << 9);
            __builtin_amdgcn_global_load_lds((const gl_u32*)(const void*)ga,
                                             (lds_u32*)(void*)la, 16, 0, 0);
            __builtin_amdgcn_global_load_lds((const gl_u32*)(const void*)gw,
                                             (lds_u32*)(void*)lw, 16, 0, 0);
        }
        __syncthreads();
        bf16x8 av[4], wvv[4];
#pragma unroll
        for (int mi = 0; mi < 4; ++mi)
            av[mi] = *(const bf16x8*)(const void*)(As + ((wr << 6) + (mi << 4) + frow) * 32 + kq);
#pragma unroll
        for (int ni = 0; ni < 4; ++ni)
            wvv[ni] = *(const bf16x8*)(const void*)(Ws + ((wc << 6) + (ni << 4) + frow) * 32 + kq);
#pragma unroll
        for (int mi = 0; mi < 4; ++mi)
#pragma unroll
            for (int ni = 0; ni < 4; ++ni)
                acc[mi][ni] = __builtin_amdgcn_mfma_f32_16x16x32_bf16(av[mi], wvv[ni], acc[mi][ni], 0, 0, 0);
        __syncthreads();
    }

#pragma unroll
    for (int mi = 0; mi < 4; ++mi) {
        const int row0 = tm + (wr << 6) + (mi << 4) + ((l >> 4) << 2);
#pragma unroll
        for (int ni = 0; ni < 4; ++ni) {
            const int col = tn + (wc << 6) + (ni << 4) + frow;
            const float bv = bias ? bias[col] : 0.0f;
#pragma unroll
            for (int r = 0; r < 4; ++r) {
                const int row = row0 + r;
                const float e = acc[mi][ni][r] + bv;
                if (mode == 0) {
                    Cb[(size_t)row * ldcb + col] = f2b(e);
                } else if (mode == 1) {
                    Cf[(size_t)row * ldc + col] = e;
                } else {
                    const size_t sidx = (size_t)row * 128 + col;
                    const float sold = step_init ? 0.0f : stepP[sidx];
                    stepP[sidx] = sold + e;
                    if (upd_cum) {
                        const float cold = step_init ? 0.0f : cumP[sidx];
                        const float cn = cold + e;
                        cumP[sidx] = cn;
                        decCum[(size_t)row * 1152 + col] = f2b(cn);
                    }
                }
            }
        }
    }
}

// GRU pointwise gates: r,z,n -> h_new. gi/gh fp32 (B,3072). Writes fp32 h_new
// (d_out hidden slice), bf16 h_new (next layer input, stride ldx), and for the
// last layer zeroes the cum columns of dec_in.
__global__ void gru_gates(const float* __restrict__ gi, const float* __restrict__ gh,
                          const float* __restrict__ hprev, float* __restrict__ hout,
                          u16* __restrict__ xlout, int ldx, u16* __restrict__ cumz)
{
    const int t = blockIdx.x * 256 + threadIdx.x;   // B*H/4 threads exactly
    const int i = t >> 8;
    const int jb = (t & 255) << 2;
    const size_t gb = (size_t)i * 3072 + jb;
    f32x4 ir = *(const f32x4*)(gi + gb);
    f32x4 iz = *(const f32x4*)(gi + gb + 1024);
    f32x4 inn = *(const f32x4*)(gi + gb + 2048);
    f32x4 hr = *(const f32x4*)(gh + gb);
    f32x4 hz = *(const f32x4*)(gh + gb + 1024);
    f32x4 hn = *(const f32x4*)(gh + gb + 2048);
    f32x4 hp = *(const f32x4*)(hprev + (size_t)i * 1024 + jb);
    f32x4 ho;
    u16x4 xo;
#pragma unroll
    for (int e = 0; e < 4; ++e) {
        float r = sigm(ir[e] + hr[e]);
        float z = sigm(iz[e] + hz[e]);
        float n = tanhf(inn[e] + r * hn[e]);
        float h = (1.0f - z) * n + z * hp[e];
        ho[e] = h;
        xo[e] = f2b(h);
    }
    *(f32x4*)(hout + (size_t)i * 1024 + jb) = ho;
    *(u16x4*)(xlout + (size_t)i * ldx + jb) = xo;
    if (cumz && jb < 128) {
        u16x4 zz = {0, 0, 0, 0};
        *(u16x4*)(cumz + (size_t)i * 1152 + 1024 + jb) = zz;
    }
}

// Row softmax over 1024 cols with temperature; one wave per row, bf16 out.
__global__ __launch_bounds__(256) void softmax_k(const float* __restrict__ logits,
                                                 u16* __restrict__ wout)
{
    const int row = blockIdx.x * 4 + (threadIdx.x >> 6);
    const int l = threadIdx.x & 63;
    const float* lr = logits + (size_t)row * 1024;
    f32x4 v[4];
    float m = -3.0e38f;
#pragma unroll
    for (int c = 0; c < 4; ++c) {
        v[c] = *(const f32x4*)(lr + c * 256 + l * 4);
#pragma unroll
        for (int e = 0; e < 4; ++e) m = fmaxf(m, v[c][e]);
    }
#pragma unroll
    for (int off = 32; off >= 1; off >>= 1) m = fmaxf(m, __shfl_xor(m, off, 64));
    float s = 0.0f;
#pragma unroll
    for (int c = 0; c < 4; ++c)
#pragma unroll
        for (int e = 0; e < 4; ++e) {
            float t = __expf((v[c][e] - m) * INV_TAU);
            v[c][e] = t;
            s += t;
        }
#pragma unroll
    for (int off = 32; off >= 1; off >>= 1) s += __shfl_xor(s, off, 64);
    const float inv = 1.0f / s;
    u16* wr_ = wout + (size_t)row * 1024;
#pragma unroll
    for (int c = 0; c < 4; ++c) {
        u16x4 o;
#pragma unroll
        for (int e = 0; e < 4; ++e) o[e] = f2b(v[c][e] * inv);
        *(u16x4*)(wr_ + c * 256 + l * 4) = o;
    }
}

// fp32 -> bf16 bits, 4 elems/thread
__global__ void f2b4(const float* __restrict__ in, u16* __restrict__ out, int n4)
{
    const int t = blockIdx.x * 256 + threadIdx.x;
    if (t >= n4) return;
    f32x4 v = *(const f32x4*)(in + (size_t)t * 4);
    u16x4 o;
#pragma unroll
    for (int e = 0; e < 4; ++e) o[e] = f2b(v[e]);
    *(u16x4*)(out + (size_t)t * 4) = o;
}

// E_t[q][d][k] = bf16(E_eff[q][k][d])  (transpose so PV GEMM is W=(N=128,K=1024))
__global__ void prep_Et(const float* __restrict__ E, u16* __restrict__ Et)
{
    const int t = blockIdx.x * 256 + threadIdx.x;   // 8*128*256 threads
    const int q = t >> 15;
    const int rem = t & 32767;
    const int d = rem >> 8;
    const int k4 = (rem & 255) << 2;
    const float* base = E + ((size_t)q * 1024 + k4) * 128 + d;
    u16x4 o;
    o[0] = f2b(base[0]);
    o[1] = f2b(base[128]);
    o[2] = f2b(base[256]);
    o[3] = f2b(base[384]);
    *(u16x4*)(Et + ((size_t)q * 128 + d) * 1024 + k4) = o;
}

// xb (B,160) bf16: cols 0..130 = x row, 131..159 = 0
__global__ void prep_x(const float* __restrict__ x, u16* __restrict__ xb)
{
    const int t = blockIdx.x * 256 + threadIdx.x;
    if (t >= 8192 * 40) return;
    const int i = t / 40;
    const int c4 = (t % 40) * 4;
    u16x4 o;
#pragma unroll
    for (int e = 0; e < 4; ++e) {
        const int c = c4 + e;
        const float v = (c < 131) ? x[(size_t)i * 131 + c] : 0.0f;
        o[e] = f2b(v);
    }
    *(u16x4*)(xb + (size_t)i * 160 + c4) = o;
}

// W0 (1024,160): rows 0..511 = [lat_w | 0], rows 512..1023 = [0(128) | cond_w | 0]
// bias0 = [lat_b | cond_b]
__global__ void prep_w0(const float* __restrict__ lat_w, const float* __restrict__ lat_b,
                        const float* __restrict__ cnd_w, const float* __restrict__ cnd_b,
                        u16* __restrict__ w0, float* __restrict__ bias0)
{
    const int t = blockIdx.x * 256 + threadIdx.x;
    if (t >= 1024 * 40) return;
    const int j = t / 40;
    const int c4 = (t % 40) * 4;
    u16x4 o;
#pragma unroll
    for (int e = 0; e < 4; ++e) {
        const int c = c4 + e;
        float v = 0.0f;
        if (j < 512) {
            if (c < 128) v = lat_w[(size_t)j * 128 + c];
        } else {
            if (c >= 128 && c < 131) v = cnd_w[(size_t)(j - 512) * 3 + (c - 128)];
        }
        o[e] = f2b(v);
    }
    *(u16x4*)(w0 + (size_t)j * 160 + c4) = o;
    if (c4 == 0) bias0[j] = (j < 512) ? lat_b[j] : cnd_b[j - 512];
}

extern "C" void kernel_launch(void* const* d_in, const int* in_sizes, int n_in,
                              void* d_out, int out_size, void* d_ws, size_t ws_size,
                              hipStream_t stream)
{
    (void)in_sizes; (void)n_in; (void)out_size; (void)ws_size;
    const float* x     = (const float*)d_in[0];
    const float* hid   = (const float*)d_in[1];
    const float* lat_w = (const float*)d_in[2];
    const float* lat_b = (const float*)d_in[3];
    const float* cnd_w = (const float*)d_in[4];
    const float* cnd_b = (const float*)d_in[5];
    const float* w_ih  = (const float*)d_in[6];
    const float* w_hh  = (const float*)d_in[7];
    const float* b_ih  = (const float*)d_in[8];
    const float* b_hh  = (const float*)d_in[9];
    const float* decw  = (const float*)d_in[10];
    const float* decb  = (const float*)d_in[11];
    const float* Eef   = (const float*)d_in[12];

    float* out = (float*)d_out;
    float* o_logits = out;                                  // (8, 8192, 1024)
    float* o_hidden = out + (size_t)8 * 8192 * 1024;        // (4, 8192, 1024)
    float* o_step   = o_hidden + (size_t)4 * 8192 * 1024;   // (8192, 128)

    // gi/gh fp32 scratch inside the logits region (fully overwritten later
    // by the 8 logits GEMMs): 2 * 8192*3072 = 50.3M floats < 67.1M region.
    float* gi = o_logits;
    float* gh = o_logits + (size_t)8192 * 3072;

    char* ws = (char*)d_ws;
    size_t off = 0;
    auto alloc = [&](size_t bytes) -> void* {
        void* p = ws + off;
        off = (off + bytes + 255) & ~(size_t)255;
        return p;
    };
    u16* wih_b   = (u16*)alloc((size_t)4 * 3072 * 1024 * 2);
    u16* whh_b   = (u16*)alloc((size_t)4 * 3072 * 1024 * 2);
    u16* decw_b  = (u16*)alloc((size_t)8 * 1024 * 1152 * 2);
    u16* Et_b    = (u16*)alloc((size_t)8 * 128 * 1024 * 2);
    u16* w0_b    = (u16*)alloc((size_t)1024 * 160 * 2);
    float* bias0 = (float*)alloc(1024 * 4);
    u16* xb      = (u16*)alloc((size_t)8192 * 160 * 2);
    u16* xl      = (u16*)alloc((size_t)8192 * 1024 * 2);
    u16* hpb     = (u16*)alloc((size_t)8192 * 1024 * 2);
    u16* decin   = (u16*)alloc((size_t)8192 * 1152 * 2);
    u16* wsoft   = (u16*)alloc((size_t)8192 * 1024 * 2);
    float* cum   = (float*)alloc((size_t)8192 * 128 * 4);

    const dim3 blk(256);

    // --- weight / input conversions ---
    {
        const int n4 = 4 * 3072 * 1024 / 4;
        f2b4<<<(n4 + 255) / 256, blk, 0, stream>>>(w_ih, wih_b, n4);
        f2b4<<<(n4 + 255) / 256, blk, 0, stream>>>(w_hh, whh_b, n4);
        const int d4 = 8 * 1024 * 1152 / 4;
        f2b4<<<(d4 + 255) / 256, blk, 0, stream>>>(decw, decw_b, d4);
        prep_Et<<<1024, blk, 0, stream>>>(Eef, Et_b);
        prep_x<<<1280, blk, 0, stream>>>(x, xb);
        prep_w0<<<160, blk, 0, stream>>>(lat_w, lat_b, cnd_w, cnd_b, w0_b, bias0);
    }

    // --- input projection: xl(bf16) = [lat|cond] = xb @ W0^T + bias0 ---
    gemm_bt<<<dim3(1024 / 128, 8192 / 128), blk, 0, stream>>>(
        xb, 160, w0_b, 160, bias0,
        nullptr, 0, xl, 1024, 160, 0,
        nullptr, nullptr, nullptr, 0, 0);

    // --- 4-layer GRU, single timestep ---
    for (int lyr = 0; lyr < 4; ++lyr) {
        const int nh4 = 8192 * 1024 / 4;
        f2b4<<<(nh4 + 255) / 256, blk, 0, stream>>>(hid + (size_t)lyr * 8192 * 1024, hpb, nh4);
        gemm_bt<<<dim3(3072 / 128, 64), blk, 0, stream>>>(
            xl, 1024, wih_b + (size_t)lyr * 3072 * 1024, 1024,
            b_ih + (size_t)lyr * 3072, gi, 3072, nullptr, 0, 1024, 1,
            nullptr, nullptr, nullptr, 0, 0);
        gemm_bt<<<dim3(3072 / 128, 64), blk, 0, stream>>>(
            hpb, 1024, whh_b + (size_t)lyr * 3072 * 1024, 1024,
            b_hh + (size_t)lyr * 3072, gh, 3072, nullptr, 0, 1024, 1,
            nullptr, nullptr, nullptr, 0, 0);
        const bool last = (lyr == 3);
        gru_gates<<<8192, blk, 0, stream>>>(
            gi, gh, hid + (size_t)lyr * 8192 * 1024,
            o_hidden + (size_t)lyr * 8192 * 1024,
            last ? decin : xl, last ? 1152 : 1024,
            last ? decin : nullptr);
    }

    // --- 8-stage soft RVQ cascade ---
    for (int q = 0; q < 8; ++q) {
        gemm_bt<<<dim3(8, 64), blk, 0, stream>>>(
            decin, 1152, decw_b + (size_t)q * 1024 * 1152, 1152,
            decb + (size_t)q * 1024,
            o_logits + (size_t)q * 8192 * 1024, 1024, nullptr, 0, 1152, 1,
            nullptr, nullptr, nullptr, 0, 0);
        softmax_k<<<2048, blk, 0, stream>>>(o_logits + (size_t)q * 8192 * 1024, wsoft);
        gemm_bt<<<dim3(1, 64), blk, 0, stream>>>(
            wsoft, 1024, Et_b + (size_t)q * 128 * 1024, 1024, nullptr,
            nullptr, 0, nullptr, 0, 1024, 2,
            o_step, cum, decin + 1024, (q == 0) ? 1 : 0, (q < 7) ? 1 : 0);
    }
}